// Round 6
// baseline (754.026 us; speedup 1.0000x reference)
//
#include <hip/hip_runtime.h>
#include <hip/hip_bf16.h>

#define NN 50000
#define EE 800000
#define IN_DIM 64
#define HIDDEN 128
#define HEADS 4
#define HEAD_DIM 32
#define EDGE_DIM 6
#define LAYERS 2
#define NEG_SLOPE 0.2f
#define BN_EPS 1e-5f

#define SCAN_CHUNK 1024
#define NSB ((NN + SCAN_CHUNK - 1) / SCAN_CHUNK)   // 49 blocks

// ---------------------------------------------------------------------------
// Edge-index dtype armor: detect int64 vs int32 layout on-device, normalize
// into clean int32 src/dst arrays (+clamp).
// ---------------------------------------------------------------------------
__global__ void detect_i64(const int* __restrict__ ei, int* __restrict__ flag) {
    int e = blockIdx.x * 256 + threadIdx.x;
    if (e < EE) {
        if (ei[2 * e + 1] != 0) atomicOr(flag, 1);   // int32 layout signature
    }
}

__global__ void normalize_edges(const int* __restrict__ ei, const int* __restrict__ flag,
                                int* __restrict__ src, int* __restrict__ dst) {
    int e = blockIdx.x * 256 + threadIdx.x;
    if (e >= EE) return;
    int s, d;
    if (*flag == 0) {              // int64 layout: low words at even positions
        s = ei[2 * e];
        d = ei[2 * EE + 2 * e];
    } else {                       // int32 layout
        s = ei[e];
        d = ei[EE + e];
    }
    s = (s < 0) ? 0 : ((s >= NN) ? NN - 1 : s);
    d = (d < 0) ? 0 : ((d >= NN) ? NN - 1 : d);
    src[e] = s;
    dst[e] = d;
}

// ---------------------------------------------------------------------------
// Counting sort of edges by destination node (built once, reused by layers)
// ---------------------------------------------------------------------------
__global__ void count_edges(const int* __restrict__ dst, int* __restrict__ counts) {
    int e = blockIdx.x * 256 + threadIdx.x;
    if (e < EE) atomicAdd(&counts[dst[e]], 1);
}

// Stage 1: per-block (1024-element chunk) sums
__global__ void scan_partial(const int* __restrict__ counts, int* __restrict__ bsum) {
    __shared__ int ws[4];
    const int tid = threadIdx.x;
    const int lane = tid & 63, wid = tid >> 6;
    int i0 = blockIdx.x * SCAN_CHUNK + tid * 4;
    int s = 0;
    #pragma unroll
    for (int k = 0; k < 4; ++k) {
        int i = i0 + k;
        if (i < NN) s += counts[i];
    }
    #pragma unroll
    for (int ofs = 1; ofs < 64; ofs <<= 1) s += __shfl_xor(s, ofs, 64);
    if (lane == 0) ws[wid] = s;
    __syncthreads();
    if (tid == 0) bsum[blockIdx.x] = ws[0] + ws[1] + ws[2] + ws[3];
}

// Stage 2: exclusive scan of the NSB (<=64) block sums, single wave
__global__ void scan_bsum(int* __restrict__ bsum) {
    int lane = threadIdx.x;
    int v = (lane < NSB) ? bsum[lane] : 0;
    int x = v;
    #pragma unroll
    for (int ofs = 1; ofs < 64; ofs <<= 1) {
        int t = __shfl_up(x, ofs, 64);
        if (lane >= ofs) x += t;
    }
    if (lane < NSB) bsum[lane] = x - v;   // exclusive
}

// Stage 3: intra-chunk exclusive scan + block offset -> offsets, cursor
__global__ void scan_final(const int* __restrict__ counts, const int* __restrict__ bsumX,
                           int* __restrict__ offsets, int* __restrict__ cursor) {
    __shared__ int ws[4];
    const int tid = threadIdx.x;
    const int lane = tid & 63, wid = tid >> 6;
    const int b = blockIdx.x;
    int i0 = b * SCAN_CHUNK + tid * 4;
    int v[4];
    int tsum = 0;
    #pragma unroll
    for (int k = 0; k < 4; ++k) {
        int i = i0 + k;
        v[k] = (i < NN) ? counts[i] : 0;
        tsum += v[k];
    }
    int x = tsum;
    #pragma unroll
    for (int ofs = 1; ofs < 64; ofs <<= 1) {
        int t = __shfl_up(x, ofs, 64);
        if (lane >= ofs) x += t;
    }
    if (lane == 63) ws[wid] = x;
    __syncthreads();
    int woff = 0;
    for (int w = 0; w < wid; ++w) woff += ws[w];
    int excl = (x - tsum) + woff + bsumX[b];
    #pragma unroll
    for (int k = 0; k < 4; ++k) {
        int i = i0 + k;
        if (i < NN) { offsets[i] = excl; cursor[i] = excl; }
        excl += v[k];
    }
    if (b == 0 && tid == 0) offsets[NN] = EE;   // total is exactly E
}

__global__ void bucket_edges(const int* __restrict__ dst, int* __restrict__ cursor,
                             int* __restrict__ sorted) {
    int e = blockIdx.x * 256 + threadIdx.x;
    if (e < EE) {
        int p = atomicAdd(&cursor[dst[e]], 1);
        sorted[p] = e;
    }
}

// ---------------------------------------------------------------------------
// fp32 GEMM: out[n,128] = A[n,K] @ W[K,128] + b  (+ReLU). For input proj.
// ---------------------------------------------------------------------------
template <int K, bool RELU>
__launch_bounds__(256, 2)
__global__ void gemm_k(const float* __restrict__ A, const float* __restrict__ W,
                       const float* __restrict__ bias, float* __restrict__ out, int n) {
    constexpr int KC = 64;
    constexpr int NCH = K / KC;
    __shared__ float Ws[KC][128];   // 32 KB
    __shared__ float As[32][KC];    // 8 KB
    const int tid = threadIdx.x;
    const int tx = tid & 31;        // cols tx*4 .. tx*4+3
    const int ty = tid >> 5;        // rows ty*4 .. ty*4+3
    const int row0 = blockIdx.x * 32;

    float acc[4][4] = {};

    for (int ch = 0; ch < NCH; ++ch) {
        const float* Wp = W + ch * KC * 128;
        for (int i = tid * 4; i < KC * 128; i += 256 * 4)
            *(float4*)&((float*)Ws)[i] = *(const float4*)&Wp[i];
        for (int i = tid * 4; i < 32 * KC; i += 256 * 4) {
            int r = i / KC, c = i % KC;
            int gr = row0 + r;
            float4 v = {0.f, 0.f, 0.f, 0.f};
            if (gr < n) v = *(const float4*)&A[gr * K + ch * KC + c];
            *(float4*)&As[r][c] = v;
        }
        __syncthreads();

        #pragma unroll 4
        for (int k4 = 0; k4 < KC; k4 += 4) {
            float4 av4[4];
            float aa[4][4];
            #pragma unroll
            for (int i = 0; i < 4; ++i) av4[i] = *(float4*)&As[ty * 4 + i][k4];
            #pragma unroll
            for (int i = 0; i < 4; ++i) {
                aa[i][0] = av4[i].x; aa[i][1] = av4[i].y;
                aa[i][2] = av4[i].z; aa[i][3] = av4[i].w;
            }
            #pragma unroll
            for (int j = 0; j < 4; ++j) {
                float4 w = *(float4*)&Ws[k4 + j][tx * 4];
                #pragma unroll
                for (int i = 0; i < 4; ++i) {
                    acc[i][0] += aa[i][j] * w.x;
                    acc[i][1] += aa[i][j] * w.y;
                    acc[i][2] += aa[i][j] * w.z;
                    acc[i][3] += aa[i][j] * w.w;
                }
            }
        }
        __syncthreads();
    }

    float4 bv = *(const float4*)&bias[tx * 4];
    #pragma unroll
    for (int i = 0; i < 4; ++i) {
        int gr = row0 + ty * 4 + i;
        if (gr < n) {
            float4 o;
            o.x = acc[i][0] + bv.x;
            o.y = acc[i][1] + bv.y;
            o.z = acc[i][2] + bv.z;
            o.w = acc[i][3] + bv.w;
            if (RELU) {
                o.x = fmaxf(o.x, 0.f); o.y = fmaxf(o.y, 0.f);
                o.z = fmaxf(o.z, 0.f); o.w = fmaxf(o.w, 0.f);
            }
            *(float4*)&out[gr * 128 + tx * 4] = o;
        }
    }
}

// ---------------------------------------------------------------------------
// Dual fp32 GEMM sharing the A operand: out1 = A@W1+b1, out2 = A@W2+b2.
// ---------------------------------------------------------------------------
__launch_bounds__(256, 2)
__global__ void gemm_dual(const float* __restrict__ A,
                          const float* __restrict__ W1, const float* __restrict__ b1,
                          const float* __restrict__ W2, const float* __restrict__ b2,
                          float* __restrict__ out1, float* __restrict__ out2, int n) {
    constexpr int K = 128, KC = 32;
    __shared__ float W1s[KC][128];  // 16 KB
    __shared__ float W2s[KC][128];  // 16 KB
    __shared__ float As[32][KC];    // 4 KB
    const int tid = threadIdx.x;
    const int tx = tid & 31;
    const int ty = tid >> 5;
    const int row0 = blockIdx.x * 32;

    float acc1[4][4] = {}, acc2[4][4] = {};

    for (int ch = 0; ch < K / KC; ++ch) {
        const float* W1p = W1 + ch * KC * 128;
        const float* W2p = W2 + ch * KC * 128;
        for (int i = tid * 4; i < KC * 128; i += 256 * 4) {
            *(float4*)&((float*)W1s)[i] = *(const float4*)&W1p[i];
            *(float4*)&((float*)W2s)[i] = *(const float4*)&W2p[i];
        }
        {   // 32x32 A tile: exactly one float4 per thread
            int i = tid * 4;
            int r = i / KC, c = i % KC;
            int gr = row0 + r;
            float4 v = {0.f, 0.f, 0.f, 0.f};
            if (gr < n) v = *(const float4*)&A[gr * K + ch * KC + c];
            *(float4*)&As[r][c] = v;
        }
        __syncthreads();

        #pragma unroll
        for (int k4 = 0; k4 < KC; k4 += 4) {
            float4 av4[4];
            float aa[4][4];
            #pragma unroll
            for (int i = 0; i < 4; ++i) av4[i] = *(float4*)&As[ty * 4 + i][k4];
            #pragma unroll
            for (int i = 0; i < 4; ++i) {
                aa[i][0] = av4[i].x; aa[i][1] = av4[i].y;
                aa[i][2] = av4[i].z; aa[i][3] = av4[i].w;
            }
            #pragma unroll
            for (int j = 0; j < 4; ++j) {
                float4 w1 = *(float4*)&W1s[k4 + j][tx * 4];
                float4 w2 = *(float4*)&W2s[k4 + j][tx * 4];
                #pragma unroll
                for (int i = 0; i < 4; ++i) {
                    acc1[i][0] += aa[i][j] * w1.x;
                    acc1[i][1] += aa[i][j] * w1.y;
                    acc1[i][2] += aa[i][j] * w1.z;
                    acc1[i][3] += aa[i][j] * w1.w;
                    acc2[i][0] += aa[i][j] * w2.x;
                    acc2[i][1] += aa[i][j] * w2.y;
                    acc2[i][2] += aa[i][j] * w2.z;
                    acc2[i][3] += aa[i][j] * w2.w;
                }
            }
        }
        __syncthreads();
    }

    float4 bv1 = *(const float4*)&b1[tx * 4];
    float4 bv2 = *(const float4*)&b2[tx * 4];
    #pragma unroll
    for (int i = 0; i < 4; ++i) {
        int gr = row0 + ty * 4 + i;
        if (gr < n) {
            float4 o1, o2;
            o1.x = acc1[i][0] + bv1.x; o1.y = acc1[i][1] + bv1.y;
            o1.z = acc1[i][2] + bv1.z; o1.w = acc1[i][3] + bv1.w;
            o2.x = acc2[i][0] + bv2.x; o2.y = acc2[i][1] + bv2.y;
            o2.z = acc2[i][2] + bv2.z; o2.w = acc2[i][3] + bv2.w;
            *(float4*)&out1[gr * 128 + tx * 4] = o1;
            *(float4*)&out2[gr * 128 + tx * 4] = o2;
        }
    }
}

// ---------------------------------------------------------------------------
// Fused GATv2 aggregation: one wave per destination node. UNIFORM control
// flow: all 64 lanes process every edge together (2 channels/lane), with a
// 2-deep prefetch guarded only by the wave-uniform condition (j+1 < cnt).
// Every __shfl executes with all lanes active and a uniform index.
// ---------------------------------------------------------------------------
__launch_bounds__(256, 4)
__global__ void gat_agg(const float* __restrict__ xl, const float* __restrict__ xr,
                        const float* __restrict__ edge_attr,
                        const int* __restrict__ src,
                        const int* __restrict__ sorted, const int* __restrict__ offsets,
                        const float* __restrict__ We, const float* __restrict__ be,
                        const float* __restrict__ att, const float* __restrict__ cbias,
                        float* __restrict__ y) {
    __shared__ float sWe[EDGE_DIM][128];
    __shared__ float sbe[128];
    __shared__ float satt[128];
    __shared__ float scb[128];
    const int tid = threadIdx.x;
    for (int i = tid; i < EDGE_DIM * 128; i += 256) ((float*)sWe)[i] = We[i];
    if (tid < 128) { sbe[tid] = be[tid]; satt[tid] = att[tid]; scb[tid] = cbias[tid]; }
    __syncthreads();

    const int wid = tid >> 6, lane = tid & 63;
    const int node = blockIdx.x * 4 + wid;
    if (node >= NN) return;

    const int c0 = lane * 2;       // this lane's 2 channels
    float2 xrv  = *(const float2*)&xr[(size_t)node * 128 + c0];
    float2 attv = *(const float2*)&satt[c0];
    float2 bev  = *(const float2*)&sbe[c0];

    const int off = offsets[node];
    const int deg = offsets[node + 1] - off;

    float mrun = -1e30f, den = 0.f, a0 = 0.f, a1 = 0.f;

    for (int base = 0; base < deg; base += 64) {
        int i = base + lane;
        int eidL = 0, sL = 0;
        if (i < deg) { eidL = sorted[off + i]; sL = src[eidL]; }
        const int cnt = min(64, deg - base);   // wave-uniform

        // prologue: load edge 0 of this chunk (uniform index, all lanes active)
        int s0 = __shfl(sL, 0, 64);
        int e0 = __shfl(eidL, 0, 64);
        float2 xlv = *(const float2*)&xl[(size_t)s0 * 128 + c0];
        float ea[EDGE_DIM];
        {
            const float* p = &edge_attr[(size_t)e0 * EDGE_DIM];
            #pragma unroll
            for (int k = 0; k < EDGE_DIM; ++k) ea[k] = p[k];
        }

        for (int j = 0; j < cnt; ++j) {
            // wave-uniform prefetch of edge j+1
            float2 xlvN = {0.f, 0.f};
            float eaN[EDGE_DIM] = {};
            if (j + 1 < cnt) {
                int sN = __shfl(sL, j + 1, 64);
                int eN = __shfl(eidL, j + 1, 64);
                xlvN = *(const float2*)&xl[(size_t)sN * 128 + c0];
                const float* p = &edge_attr[(size_t)eN * EDGE_DIM];
                #pragma unroll
                for (int k = 0; k < EDGE_DIM; ++k) eaN[k] = p[k];
            }
            // compute current edge
            float m0 = xlv.x + xrv.x + bev.x;
            float m1 = xlv.y + xrv.y + bev.y;
            #pragma unroll
            for (int k = 0; k < EDGE_DIM; ++k) {
                float2 w = *(const float2*)&sWe[k][c0];
                m0 += ea[k] * w.x;
                m1 += ea[k] * w.y;
            }
            m0 = (m0 > 0.f) ? m0 : m0 * NEG_SLOPE;
            m1 = (m1 > 0.f) ? m1 : m1 * NEG_SLOPE;
            float t = m0 * attv.x + m1 * attv.y;
            // head = 32 channels = 16 consecutive lanes; reduce over bits 0-3
            t += __shfl_xor(t, 1, 64);
            t += __shfl_xor(t, 2, 64);
            t += __shfl_xor(t, 4, 64);
            t += __shfl_xor(t, 8, 64);
            float nm = fmaxf(mrun, t);
            float sc = __expf(mrun - nm);
            float p  = __expf(t - nm);
            den = den * sc + p;
            a0  = a0 * sc + p * xlv.x;
            a1  = a1 * sc + p * xlv.y;
            mrun = nm;
            // rotate pipeline
            xlv = xlvN;
            #pragma unroll
            for (int k = 0; k < EDGE_DIM; ++k) ea[k] = eaN[k];
        }
    }

    float o0 = scb[c0], o1 = scb[c0 + 1];
    if (deg > 0) {
        float inv = 1.f / den;
        o0 += a0 * inv;
        o1 += a1 * inv;
    }
    float2 r; r.x = o0; r.y = o1;
    *(float2*)&y[(size_t)node * 128 + c0] = r;
}

// ---------------------------------------------------------------------------
// BatchNorm: per-channel stats then apply + ReLU
// ---------------------------------------------------------------------------
__global__ void bn_stats(const float* __restrict__ y, float* __restrict__ gsum,
                         float* __restrict__ gsq) {
    __shared__ float ls[128], lq[128];
    const int tid = threadIdx.x;
    if (tid < 128) { ls[tid] = 0.f; lq[tid] = 0.f; }
    __syncthreads();
    int idx = blockIdx.x * 256 + tid;        // float4 units
    const int stride = gridDim.x * 256;      // multiple of 32 -> c4 constant
    const int c4 = (idx & 31) * 4;
    float s[4] = {}, q[4] = {};
    for (; idx < NN * 32; idx += stride) {
        float4 v = ((const float4*)y)[idx];
        s[0] += v.x; q[0] += v.x * v.x;
        s[1] += v.y; q[1] += v.y * v.y;
        s[2] += v.z; q[2] += v.z * v.z;
        s[3] += v.w; q[3] += v.w * v.w;
    }
    #pragma unroll
    for (int j = 0; j < 4; ++j) {
        atomicAdd(&ls[c4 + j], s[j]);
        atomicAdd(&lq[c4 + j], q[j]);
    }
    __syncthreads();
    if (tid < 128) {
        atomicAdd(&gsum[tid], ls[tid]);
        atomicAdd(&gsq[tid],  lq[tid]);
    }
}

__global__ void bn_apply(const float* __restrict__ y, const float* __restrict__ gsum,
                         const float* __restrict__ gsq, const float* __restrict__ gamma,
                         const float* __restrict__ beta, float* __restrict__ out) {
    int idx = blockIdx.x * 256 + threadIdx.x;   // float4 index
    const int stride = gridDim.x * 256;         // multiple of 32 -> c4 constant
    const int c4 = (idx & 31) * 4;
    const float invN = 1.f / (float)NN;
    float sc[4], sh[4];
    #pragma unroll
    for (int j = 0; j < 4; ++j) {
        int c = c4 + j;
        float mu  = gsum[c] * invN;
        float var = fmaxf(gsq[c] * invN - mu * mu, 0.f);
        sc[j] = rsqrtf(var + BN_EPS) * gamma[c];
        sh[j] = beta[c] - mu * sc[j];
    }
    for (; idx < NN * 32; idx += stride) {
        float4 v = ((const float4*)y)[idx];
        float4 o;
        o.x = fmaxf(v.x * sc[0] + sh[0], 0.f);
        o.y = fmaxf(v.y * sc[1] + sh[1], 0.f);
        o.z = fmaxf(v.z * sc[2] + sh[2], 0.f);
        o.w = fmaxf(v.w * sc[3] + sh[3], 0.f);
        ((float4*)out)[idx] = o;
    }
}

// ---------------------------------------------------------------------------
extern "C" void kernel_launch(void* const* d_in, const int* in_sizes, int n_in,
                              void* d_out, int out_size, void* d_ws, size_t ws_size,
                              hipStream_t stream) {
    const float* x        = (const float*)d_in[0];
    const int*   eidx     = (const int*)d_in[1];      // [2,E], layout auto-detected
    const float* edge_attr= (const float*)d_in[2];
    const float* Wproj    = (const float*)d_in[3];
    const float* bproj    = (const float*)d_in[4];
    const float* Wl       = (const float*)d_in[5];
    const float* bl       = (const float*)d_in[6];
    const float* Wr       = (const float*)d_in[7];
    const float* br       = (const float*)d_in[8];
    const float* We       = (const float*)d_in[9];
    const float* be       = (const float*)d_in[10];
    const float* att      = (const float*)d_in[11];
    const float* cbias    = (const float*)d_in[12];
    const float* gamma    = (const float*)d_in[13];
    const float* beta     = (const float*)d_in[14];

    char* ws = (char*)d_ws;
    auto alloc = [&](size_t bytes) {
        char* p = ws;
        ws += (bytes + 255) & ~(size_t)255;
        return p;
    };
    float* h      = (float*)alloc((size_t)NN * 128 * 4);  // pre-BN buffer (in-place BN)
    float* xlB    = (float*)alloc((size_t)NN * 128 * 4);
    float* xrB    = (float*)alloc((size_t)NN * 128 * 4);
    int*   srcN   = (int*)alloc((size_t)EE * 4);
    int*   dstN   = (int*)alloc((size_t)EE * 4);
    int*   counts = (int*)alloc((size_t)NN * 4);
    int*   offs   = (int*)alloc((size_t)(NN + 1) * 4);
    int*   cursor = (int*)alloc((size_t)NN * 4);
    int*   sorted = (int*)alloc((size_t)EE * 4);
    int*   bsum   = (int*)alloc((size_t)NSB * 4);
    int*   flag   = (int*)alloc(256);
    float* gsum   = (float*)alloc((size_t)LAYERS * 128 * 4);
    float* gsq    = (float*)alloc((size_t)LAYERS * 128 * 4);

    hipMemsetAsync(counts, 0, (size_t)NN * 4, stream);
    hipMemsetAsync(flag, 0, 4, stream);
    hipMemsetAsync(gsum, 0, (size_t)LAYERS * 128 * 4, stream);
    hipMemsetAsync(gsq,  0, (size_t)LAYERS * 128 * 4, stream);

    // normalize edge_index to int32 src/dst regardless of int32/int64 layout
    detect_i64<<<(EE + 255) / 256, 256, 0, stream>>>(eidx, flag);
    normalize_edges<<<(EE + 255) / 256, 256, 0, stream>>>(eidx, flag, srcN, dstN);

    // bucket edges by dst (parallel counting sort, shared by both layers)
    count_edges<<<(EE + 255) / 256, 256, 0, stream>>>(dstN, counts);
    scan_partial<<<NSB, 256, 0, stream>>>(counts, bsum);
    scan_bsum<<<1, 64, 0, stream>>>(bsum);
    scan_final<<<NSB, 256, 0, stream>>>(counts, bsum, offs, cursor);
    bucket_edges<<<(EE + 255) / 256, 256, 0, stream>>>(dstN, cursor, sorted);

    // input projection + ReLU
    gemm_k<IN_DIM, true><<<(NN + 31) / 32, 256, 0, stream>>>(x, Wproj, bproj, h, NN);

    for (int l = 0; l < LAYERS; ++l) {
        gemm_dual<<<(NN + 31) / 32, 256, 0, stream>>>(
            h,
            Wl + (size_t)l * 128 * 128, bl + l * 128,
            Wr + (size_t)l * 128 * 128, br + l * 128,
            xlB, xrB, NN);
        gat_agg<<<(NN + 3) / 4, 256, 0, stream>>>(
            xlB, xrB, edge_attr, srcN, sorted, offs,
            We + (size_t)l * EDGE_DIM * 128, be + l * 128, att + l * 128,
            cbias + l * 128, h);
        bn_stats<<<400, 256, 0, stream>>>(h, gsum + l * 128, gsq + l * 128);
        float* outp = (l == LAYERS - 1) ? (float*)d_out : h;
        bn_apply<<<512, 256, 0, stream>>>(h, gsum + l * 128, gsq + l * 128,
                                          gamma + l * 128, beta + l * 128, outp);
    }
}

// Round 7
// 647.664 us; speedup vs baseline: 1.1642x; 1.1642x over previous
//
#include <hip/hip_runtime.h>
#include <hip/hip_bf16.h>

#define NN 50000
#define EE 800000
#define IN_DIM 64
#define HIDDEN 128
#define HEADS 4
#define HEAD_DIM 32
#define EDGE_DIM 6
#define LAYERS 2
#define NEG_SLOPE 0.2f
#define BN_EPS 1e-5f

#define SCAN_CHUNK 1024
#define NSB ((NN + SCAN_CHUNK - 1) / SCAN_CHUNK)   // 49 blocks

// ---------------------------------------------------------------------------
// Edge-index dtype armor, v2: single-block sampled detector (no atomics).
// Samples 16384 odd dwords; int64 layout (values < 2^31) has all == 0.
// For int32 layout those words are node ids, ~all nonzero. P(miss) ~ 0.
// ---------------------------------------------------------------------------
__global__ void detect_layout(const int* __restrict__ ei, int* __restrict__ flag) {
    __shared__ int any;
    if (threadIdx.x == 0) any = 0;
    __syncthreads();
    int found = 0;
    #pragma unroll
    for (int k = 0; k < 16; ++k) {
        int e = threadIdx.x + k * 1024;       // first 16384 edges; 2e+1 << 1.6M
        if (ei[2 * e + 1] != 0) found = 1;
    }
    if (found) any = 1;                       // benign race: all writers write 1
    __syncthreads();
    if (threadIdx.x == 0) *flag = any;        // unconditional, deterministic
}

__global__ void normalize_edges(const int* __restrict__ ei, const int* __restrict__ flag,
                                int* __restrict__ src, int* __restrict__ dst) {
    int e = blockIdx.x * 256 + threadIdx.x;
    if (e >= EE) return;
    int s, d;
    if (*flag == 0) {              // int64 layout: low words at even positions
        s = ei[2 * e];
        d = ei[2 * EE + 2 * e];
    } else {                       // int32 layout
        s = ei[e];
        d = ei[EE + e];
    }
    s = (s < 0) ? 0 : ((s >= NN) ? NN - 1 : s);
    d = (d < 0) ? 0 : ((d >= NN) ? NN - 1 : d);
    src[e] = s;
    dst[e] = d;
}

// ---------------------------------------------------------------------------
// Counting sort of edges by destination node (built once, reused by layers)
// ---------------------------------------------------------------------------
__global__ void count_edges(const int* __restrict__ dst, int* __restrict__ counts) {
    int e = blockIdx.x * 256 + threadIdx.x;
    if (e < EE) atomicAdd(&counts[dst[e]], 1);
}

// Stage 1: per-block (1024-element chunk) sums
__global__ void scan_partial(const int* __restrict__ counts, int* __restrict__ bsum) {
    __shared__ int ws[4];
    const int tid = threadIdx.x;
    const int lane = tid & 63, wid = tid >> 6;
    int i0 = blockIdx.x * SCAN_CHUNK + tid * 4;
    int s = 0;
    #pragma unroll
    for (int k = 0; k < 4; ++k) {
        int i = i0 + k;
        if (i < NN) s += counts[i];
    }
    #pragma unroll
    for (int ofs = 1; ofs < 64; ofs <<= 1) s += __shfl_xor(s, ofs, 64);
    if (lane == 0) ws[wid] = s;
    __syncthreads();
    if (tid == 0) bsum[blockIdx.x] = ws[0] + ws[1] + ws[2] + ws[3];
}

// Stage 2: exclusive scan of the NSB (<=64) block sums, single wave
__global__ void scan_bsum(int* __restrict__ bsum) {
    int lane = threadIdx.x;
    int v = (lane < NSB) ? bsum[lane] : 0;
    int x = v;
    #pragma unroll
    for (int ofs = 1; ofs < 64; ofs <<= 1) {
        int t = __shfl_up(x, ofs, 64);
        if (lane >= ofs) x += t;
    }
    if (lane < NSB) bsum[lane] = x - v;   // exclusive
}

// Stage 3: intra-chunk exclusive scan + block offset -> offsets, cursor
__global__ void scan_final(const int* __restrict__ counts, const int* __restrict__ bsumX,
                           int* __restrict__ offsets, int* __restrict__ cursor) {
    __shared__ int ws[4];
    const int tid = threadIdx.x;
    const int lane = tid & 63, wid = tid >> 6;
    const int b = blockIdx.x;
    int i0 = b * SCAN_CHUNK + tid * 4;
    int v[4];
    int tsum = 0;
    #pragma unroll
    for (int k = 0; k < 4; ++k) {
        int i = i0 + k;
        v[k] = (i < NN) ? counts[i] : 0;
        tsum += v[k];
    }
    int x = tsum;
    #pragma unroll
    for (int ofs = 1; ofs < 64; ofs <<= 1) {
        int t = __shfl_up(x, ofs, 64);
        if (lane >= ofs) x += t;
    }
    if (lane == 63) ws[wid] = x;
    __syncthreads();
    int woff = 0;
    for (int w = 0; w < wid; ++w) woff += ws[w];
    int excl = (x - tsum) + woff + bsumX[b];
    #pragma unroll
    for (int k = 0; k < 4; ++k) {
        int i = i0 + k;
        if (i < NN) { offsets[i] = excl; cursor[i] = excl; }
        excl += v[k];
    }
    if (b == 0 && tid == 0) offsets[NN] = EE;   // total is exactly E
}

__global__ void bucket_edges(const int* __restrict__ dst, int* __restrict__ cursor,
                             int* __restrict__ sorted) {
    int e = blockIdx.x * 256 + threadIdx.x;
    if (e < EE) {
        int p = atomicAdd(&cursor[dst[e]], 1);
        sorted[p] = e;
    }
}

// ---------------------------------------------------------------------------
// fp32 GEMM: out[n,128] = A[n,K] @ W[K,128] + b  (+ReLU). For input proj.
// ---------------------------------------------------------------------------
template <int K, bool RELU>
__launch_bounds__(256, 2)
__global__ void gemm_k(const float* __restrict__ A, const float* __restrict__ W,
                       const float* __restrict__ bias, float* __restrict__ out, int n) {
    constexpr int KC = 64;
    constexpr int NCH = K / KC;
    __shared__ float Ws[KC][128];   // 32 KB
    __shared__ float As[32][KC];    // 8 KB
    const int tid = threadIdx.x;
    const int tx = tid & 31;        // cols tx*4 .. tx*4+3
    const int ty = tid >> 5;        // rows ty*4 .. ty*4+3
    const int row0 = blockIdx.x * 32;

    float acc[4][4] = {};

    for (int ch = 0; ch < NCH; ++ch) {
        const float* Wp = W + ch * KC * 128;
        for (int i = tid * 4; i < KC * 128; i += 256 * 4)
            *(float4*)&((float*)Ws)[i] = *(const float4*)&Wp[i];
        for (int i = tid * 4; i < 32 * KC; i += 256 * 4) {
            int r = i / KC, c = i % KC;
            int gr = row0 + r;
            float4 v = {0.f, 0.f, 0.f, 0.f};
            if (gr < n) v = *(const float4*)&A[gr * K + ch * KC + c];
            *(float4*)&As[r][c] = v;
        }
        __syncthreads();

        #pragma unroll 4
        for (int k4 = 0; k4 < KC; k4 += 4) {
            float4 av4[4];
            float aa[4][4];
            #pragma unroll
            for (int i = 0; i < 4; ++i) av4[i] = *(float4*)&As[ty * 4 + i][k4];
            #pragma unroll
            for (int i = 0; i < 4; ++i) {
                aa[i][0] = av4[i].x; aa[i][1] = av4[i].y;
                aa[i][2] = av4[i].z; aa[i][3] = av4[i].w;
            }
            #pragma unroll
            for (int j = 0; j < 4; ++j) {
                float4 w = *(float4*)&Ws[k4 + j][tx * 4];
                #pragma unroll
                for (int i = 0; i < 4; ++i) {
                    acc[i][0] += aa[i][j] * w.x;
                    acc[i][1] += aa[i][j] * w.y;
                    acc[i][2] += aa[i][j] * w.z;
                    acc[i][3] += aa[i][j] * w.w;
                }
            }
        }
        __syncthreads();
    }

    float4 bv = *(const float4*)&bias[tx * 4];
    #pragma unroll
    for (int i = 0; i < 4; ++i) {
        int gr = row0 + ty * 4 + i;
        if (gr < n) {
            float4 o;
            o.x = acc[i][0] + bv.x;
            o.y = acc[i][1] + bv.y;
            o.z = acc[i][2] + bv.z;
            o.w = acc[i][3] + bv.w;
            if (RELU) {
                o.x = fmaxf(o.x, 0.f); o.y = fmaxf(o.y, 0.f);
                o.z = fmaxf(o.z, 0.f); o.w = fmaxf(o.w, 0.f);
            }
            *(float4*)&out[gr * 128 + tx * 4] = o;
        }
    }
}

// ---------------------------------------------------------------------------
// Dual fp32 GEMM sharing the A operand: out1 = A@W1+b1, out2 = A@W2+b2.
// ---------------------------------------------------------------------------
__launch_bounds__(256, 2)
__global__ void gemm_dual(const float* __restrict__ A,
                          const float* __restrict__ W1, const float* __restrict__ b1,
                          const float* __restrict__ W2, const float* __restrict__ b2,
                          float* __restrict__ out1, float* __restrict__ out2, int n) {
    constexpr int K = 128, KC = 32;
    __shared__ float W1s[KC][128];  // 16 KB
    __shared__ float W2s[KC][128];  // 16 KB
    __shared__ float As[32][KC];    // 4 KB
    const int tid = threadIdx.x;
    const int tx = tid & 31;
    const int ty = tid >> 5;
    const int row0 = blockIdx.x * 32;

    float acc1[4][4] = {}, acc2[4][4] = {};

    for (int ch = 0; ch < K / KC; ++ch) {
        const float* W1p = W1 + ch * KC * 128;
        const float* W2p = W2 + ch * KC * 128;
        for (int i = tid * 4; i < KC * 128; i += 256 * 4) {
            *(float4*)&((float*)W1s)[i] = *(const float4*)&W1p[i];
            *(float4*)&((float*)W2s)[i] = *(const float4*)&W2p[i];
        }
        {   // 32x32 A tile: exactly one float4 per thread
            int i = tid * 4;
            int r = i / KC, c = i % KC;
            int gr = row0 + r;
            float4 v = {0.f, 0.f, 0.f, 0.f};
            if (gr < n) v = *(const float4*)&A[gr * K + ch * KC + c];
            *(float4*)&As[r][c] = v;
        }
        __syncthreads();

        #pragma unroll
        for (int k4 = 0; k4 < KC; k4 += 4) {
            float4 av4[4];
            float aa[4][4];
            #pragma unroll
            for (int i = 0; i < 4; ++i) av4[i] = *(float4*)&As[ty * 4 + i][k4];
            #pragma unroll
            for (int i = 0; i < 4; ++i) {
                aa[i][0] = av4[i].x; aa[i][1] = av4[i].y;
                aa[i][2] = av4[i].z; aa[i][3] = av4[i].w;
            }
            #pragma unroll
            for (int j = 0; j < 4; ++j) {
                float4 w1 = *(float4*)&W1s[k4 + j][tx * 4];
                float4 w2 = *(float4*)&W2s[k4 + j][tx * 4];
                #pragma unroll
                for (int i = 0; i < 4; ++i) {
                    acc1[i][0] += aa[i][j] * w1.x;
                    acc1[i][1] += aa[i][j] * w1.y;
                    acc1[i][2] += aa[i][j] * w1.z;
                    acc1[i][3] += aa[i][j] * w1.w;
                    acc2[i][0] += aa[i][j] * w2.x;
                    acc2[i][1] += aa[i][j] * w2.y;
                    acc2[i][2] += aa[i][j] * w2.z;
                    acc2[i][3] += aa[i][j] * w2.w;
                }
            }
        }
        __syncthreads();
    }

    float4 bv1 = *(const float4*)&b1[tx * 4];
    float4 bv2 = *(const float4*)&b2[tx * 4];
    #pragma unroll
    for (int i = 0; i < 4; ++i) {
        int gr = row0 + ty * 4 + i;
        if (gr < n) {
            float4 o1, o2;
            o1.x = acc1[i][0] + bv1.x; o1.y = acc1[i][1] + bv1.y;
            o1.z = acc1[i][2] + bv1.z; o1.w = acc1[i][3] + bv1.w;
            o2.x = acc2[i][0] + bv2.x; o2.y = acc2[i][1] + bv2.y;
            o2.z = acc2[i][2] + bv2.z; o2.w = acc2[i][3] + bv2.w;
            *(float4*)&out1[gr * 128 + tx * 4] = o1;
            *(float4*)&out2[gr * 128 + tx * 4] = o2;
        }
    }
}

// ---------------------------------------------------------------------------
// Fused GATv2 aggregation v2: one wave per destination node, 2-edge unroll
// with two independent online-softmax states (A = even edges, B = odd),
// merged lane-locally at the end. All __shfl ops execute with all lanes
// active and wave-uniform indices; guards are wave-uniform.
// ---------------------------------------------------------------------------
__launch_bounds__(256, 4)
__global__ void gat_agg(const float* __restrict__ xl, const float* __restrict__ xr,
                        const float* __restrict__ edge_attr,
                        const int* __restrict__ src,
                        const int* __restrict__ sorted, const int* __restrict__ offsets,
                        const float* __restrict__ We, const float* __restrict__ be,
                        const float* __restrict__ att, const float* __restrict__ cbias,
                        float* __restrict__ y) {
    __shared__ float sWe[EDGE_DIM][128];
    __shared__ float sbe[128];
    __shared__ float satt[128];
    __shared__ float scb[128];
    const int tid = threadIdx.x;
    for (int i = tid; i < EDGE_DIM * 128; i += 256) ((float*)sWe)[i] = We[i];
    if (tid < 128) { sbe[tid] = be[tid]; satt[tid] = att[tid]; scb[tid] = cbias[tid]; }
    __syncthreads();

    const int wid = tid >> 6, lane = tid & 63;
    const int node = blockIdx.x * 4 + wid;
    if (node >= NN) return;

    const int c0 = lane * 2;       // this lane's 2 channels
    float2 xrv  = *(const float2*)&xr[(size_t)node * 128 + c0];
    float2 attv = *(const float2*)&satt[c0];
    float2 bev  = *(const float2*)&sbe[c0];
    const float base0 = xrv.x + bev.x;
    const float base1 = xrv.y + bev.y;

    const int off = offsets[node];
    const int deg = offsets[node + 1] - off;

    float mA = -1e30f, dA = 0.f, aA0 = 0.f, aA1 = 0.f;
    float mB = -1e30f, dB = 0.f, aB0 = 0.f, aB1 = 0.f;

    for (int chunk = 0; chunk < deg; chunk += 64) {
        int i = chunk + lane;
        int eidL = 0, sL = 0;
        if (i < deg) { eidL = sorted[off + i]; sL = src[eidL]; }
        const int cnt = min(64, deg - chunk);   // wave-uniform

        for (int j = 0; j < cnt; j += 2) {
            const int j1 = (j + 1) & 63;        // valid lane even when unused
            int sa = __shfl(sL, j, 64);
            int ea = __shfl(eidL, j, 64);
            int sb = __shfl(sL, j1, 64);
            int eb = __shfl(eidL, j1, 64);
            // both gathers issued back-to-back (MLP >= 2)
            float2 xa = *(const float2*)&xl[(size_t)sa * 128 + c0];
            float2 xb = *(const float2*)&xl[(size_t)sb * 128 + c0];
            const float* pa = &edge_attr[(size_t)ea * EDGE_DIM];
            const float* pb = &edge_attr[(size_t)eb * EDGE_DIM];
            float ma0 = xa.x + base0, ma1 = xa.y + base1;
            float mb0 = xb.x + base0, mb1 = xb.y + base1;
            #pragma unroll
            for (int k = 0; k < EDGE_DIM; ++k) {
                float2 w = *(const float2*)&sWe[k][c0];
                float va = pa[k], vb = pb[k];
                ma0 += va * w.x; ma1 += va * w.y;
                mb0 += vb * w.x; mb1 += vb * w.y;
            }
            ma0 = (ma0 > 0.f) ? ma0 : ma0 * NEG_SLOPE;
            ma1 = (ma1 > 0.f) ? ma1 : ma1 * NEG_SLOPE;
            mb0 = (mb0 > 0.f) ? mb0 : mb0 * NEG_SLOPE;
            mb1 = (mb1 > 0.f) ? mb1 : mb1 * NEG_SLOPE;
            float ta = ma0 * attv.x + ma1 * attv.y;
            float tb = mb0 * attv.x + mb1 * attv.y;
            // head = 32 channels = 16 consecutive lanes; two independent chains
            #pragma unroll
            for (int ofs = 1; ofs <= 8; ofs <<= 1) {
                ta += __shfl_xor(ta, ofs, 64);
                tb += __shfl_xor(tb, ofs, 64);
            }
            {   // state A (edge j always valid)
                float nm = fmaxf(mA, ta);
                float sc = __expf(mA - nm);
                float p  = __expf(ta - nm);
                dA  = dA * sc + p;
                aA0 = aA0 * sc + p * xa.x;
                aA1 = aA1 * sc + p * xa.y;
                mA = nm;
            }
            if (j + 1 < cnt) {   // wave-uniform
                float nm = fmaxf(mB, tb);
                float sc = __expf(mB - nm);
                float p  = __expf(tb - nm);
                dB  = dB * sc + p;
                aB0 = aB0 * sc + p * xb.x;
                aB1 = aB1 * sc + p * xb.y;
                mB = nm;
            }
        }
    }

    // lane-local merge of states A and B
    float o0 = scb[c0], o1 = scb[c0 + 1];
    if (deg > 0) {
        float M  = fmaxf(mA, mB);
        float sA = __expf(mA - M);      // mB may be -1e30 -> sB underflows to 0
        float sB = __expf(mB - M);
        float den = dA * sA + dB * sB;
        float inv = 1.f / den;
        o0 += (aA0 * sA + aB0 * sB) * inv;
        o1 += (aA1 * sA + aB1 * sB) * inv;
    }
    float2 r; r.x = o0; r.y = o1;
    *(float2*)&y[(size_t)node * 128 + c0] = r;
}

// ---------------------------------------------------------------------------
// BatchNorm: per-channel stats then apply + ReLU
// ---------------------------------------------------------------------------
__global__ void bn_stats(const float* __restrict__ y, float* __restrict__ gsum,
                         float* __restrict__ gsq) {
    __shared__ float ls[128], lq[128];
    const int tid = threadIdx.x;
    if (tid < 128) { ls[tid] = 0.f; lq[tid] = 0.f; }
    __syncthreads();
    int idx = blockIdx.x * 256 + tid;        // float4 units
    const int stride = gridDim.x * 256;      // multiple of 32 -> c4 constant
    const int c4 = (idx & 31) * 4;
    float s[4] = {}, q[4] = {};
    for (; idx < NN * 32; idx += stride) {
        float4 v = ((const float4*)y)[idx];
        s[0] += v.x; q[0] += v.x * v.x;
        s[1] += v.y; q[1] += v.y * v.y;
        s[2] += v.z; q[2] += v.z * v.z;
        s[3] += v.w; q[3] += v.w * v.w;
    }
    #pragma unroll
    for (int j = 0; j < 4; ++j) {
        atomicAdd(&ls[c4 + j], s[j]);
        atomicAdd(&lq[c4 + j], q[j]);
    }
    __syncthreads();
    if (tid < 128) {
        atomicAdd(&gsum[tid], ls[tid]);
        atomicAdd(&gsq[tid],  lq[tid]);
    }
}

__global__ void bn_apply(const float* __restrict__ y, const float* __restrict__ gsum,
                         const float* __restrict__ gsq, const float* __restrict__ gamma,
                         const float* __restrict__ beta, float* __restrict__ out) {
    int idx = blockIdx.x * 256 + threadIdx.x;   // float4 index
    const int stride = gridDim.x * 256;         // multiple of 32 -> c4 constant
    const int c4 = (idx & 31) * 4;
    const float invN = 1.f / (float)NN;
    float sc[4], sh[4];
    #pragma unroll
    for (int j = 0; j < 4; ++j) {
        int c = c4 + j;
        float mu  = gsum[c] * invN;
        float var = fmaxf(gsq[c] * invN - mu * mu, 0.f);
        sc[j] = rsqrtf(var + BN_EPS) * gamma[c];
        sh[j] = beta[c] - mu * sc[j];
    }
    for (; idx < NN * 32; idx += stride) {
        float4 v = ((const float4*)y)[idx];
        float4 o;
        o.x = fmaxf(v.x * sc[0] + sh[0], 0.f);
        o.y = fmaxf(v.y * sc[1] + sh[1], 0.f);
        o.z = fmaxf(v.z * sc[2] + sh[2], 0.f);
        o.w = fmaxf(v.w * sc[3] + sh[3], 0.f);
        ((float4*)out)[idx] = o;
    }
}

// ---------------------------------------------------------------------------
extern "C" void kernel_launch(void* const* d_in, const int* in_sizes, int n_in,
                              void* d_out, int out_size, void* d_ws, size_t ws_size,
                              hipStream_t stream) {
    const float* x        = (const float*)d_in[0];
    const int*   eidx     = (const int*)d_in[1];      // [2,E], layout auto-detected
    const float* edge_attr= (const float*)d_in[2];
    const float* Wproj    = (const float*)d_in[3];
    const float* bproj    = (const float*)d_in[4];
    const float* Wl       = (const float*)d_in[5];
    const float* bl       = (const float*)d_in[6];
    const float* Wr       = (const float*)d_in[7];
    const float* br       = (const float*)d_in[8];
    const float* We       = (const float*)d_in[9];
    const float* be       = (const float*)d_in[10];
    const float* att      = (const float*)d_in[11];
    const float* cbias    = (const float*)d_in[12];
    const float* gamma    = (const float*)d_in[13];
    const float* beta     = (const float*)d_in[14];

    char* ws = (char*)d_ws;
    auto alloc = [&](size_t bytes) {
        char* p = ws;
        ws += (bytes + 255) & ~(size_t)255;
        return p;
    };
    float* h      = (float*)alloc((size_t)NN * 128 * 4);  // pre-BN buffer (in-place BN)
    float* xlB    = (float*)alloc((size_t)NN * 128 * 4);
    float* xrB    = (float*)alloc((size_t)NN * 128 * 4);
    int*   srcN   = (int*)alloc((size_t)EE * 4);
    int*   dstN   = (int*)alloc((size_t)EE * 4);
    int*   counts = (int*)alloc((size_t)NN * 4);
    int*   offs   = (int*)alloc((size_t)(NN + 1) * 4);
    int*   cursor = (int*)alloc((size_t)NN * 4);
    int*   sorted = (int*)alloc((size_t)EE * 4);
    int*   bsum   = (int*)alloc((size_t)NSB * 4);
    int*   flag   = (int*)alloc(256);
    float* gsum   = (float*)alloc((size_t)LAYERS * 128 * 4);
    float* gsq    = (float*)alloc((size_t)LAYERS * 128 * 4);

    hipMemsetAsync(counts, 0, (size_t)NN * 4, stream);
    hipMemsetAsync(gsum, 0, (size_t)LAYERS * 128 * 4, stream);
    hipMemsetAsync(gsq,  0, (size_t)LAYERS * 128 * 4, stream);

    // normalize edge_index to int32 src/dst regardless of int32/int64 layout
    detect_layout<<<1, 1024, 0, stream>>>(eidx, flag);
    normalize_edges<<<(EE + 255) / 256, 256, 0, stream>>>(eidx, flag, srcN, dstN);

    // bucket edges by dst (parallel counting sort, shared by both layers)
    count_edges<<<(EE + 255) / 256, 256, 0, stream>>>(dstN, counts);
    scan_partial<<<NSB, 256, 0, stream>>>(counts, bsum);
    scan_bsum<<<1, 64, 0, stream>>>(bsum);
    scan_final<<<NSB, 256, 0, stream>>>(counts, bsum, offs, cursor);
    bucket_edges<<<(EE + 255) / 256, 256, 0, stream>>>(dstN, cursor, sorted);

    // input projection + ReLU
    gemm_k<IN_DIM, true><<<(NN + 31) / 32, 256, 0, stream>>>(x, Wproj, bproj, h, NN);

    for (int l = 0; l < LAYERS; ++l) {
        gemm_dual<<<(NN + 31) / 32, 256, 0, stream>>>(
            h,
            Wl + (size_t)l * 128 * 128, bl + l * 128,
            Wr + (size_t)l * 128 * 128, br + l * 128,
            xlB, xrB, NN);
        gat_agg<<<(NN + 3) / 4, 256, 0, stream>>>(
            xlB, xrB, edge_attr, srcN, sorted, offs,
            We + (size_t)l * EDGE_DIM * 128, be + l * 128, att + l * 128,
            cbias + l * 128, h);
        bn_stats<<<400, 256, 0, stream>>>(h, gsum + l * 128, gsq + l * 128);
        float* outp = (l == LAYERS - 1) ? (float*)d_out : h;
        bn_apply<<<512, 256, 0, stream>>>(h, gsum + l * 128, gsq + l * 128,
                                          gamma + l * 128, beta + l * 128, outp);
    }
}